// Round 1
// baseline (423.885 us; speedup 1.0000x reference)
//
#include <hip/hip_runtime.h>
#include <stdint.h>
#include <stddef.h>

// Problem constants
#define N_B   32
#define C_CH  256
#define H_S   56
#define W_S   56
#define HW    (H_S*W_S)        // 3136
#define NSP   (N_B*HW)         // 100352
#define KTOT  (C_CH*9)         // 2304
#define HP    58               // padded spatial

// Workspace layout (bytes)
#define XPAD_ELEMS ((size_t)N_B*HP*HP*C_CH)        // 27,557,888
#define XPAD_BYTES (XPAD_ELEMS*2)                  // 55,115,776
#define WB_OFF_B   XPAD_BYTES
#define WB_ELEMS   ((size_t)C_CH*KTOT)             // 589,824
#define Y_OFF_B    (WB_OFF_B + WB_ELEMS*2)         // 56,295,424
#define STAT_OFF_B (Y_OFF_B + (size_t)C_CH*NSP*2)  // 107,675,648

typedef __bf16 bf16x8 __attribute__((ext_vector_type(8)));
typedef float  f32x4  __attribute__((ext_vector_type(4)));
typedef short  s16x4  __attribute__((ext_vector_type(4)));
typedef short  s16x8  __attribute__((ext_vector_type(8)));
typedef float  f32x4v __attribute__((ext_vector_type(4)));

__device__ __forceinline__ void gl16(const void* g, void* l) {
    __builtin_amdgcn_global_load_lds((const __attribute__((address_space(1))) void*)g,
                                     (__attribute__((address_space(3))) void*)l, 16, 0, 0);
}

__device__ __forceinline__ unsigned short sign_bf16(float v) {
    return v > 0.f ? 0x3F80u : (v < 0.f ? 0xBF80u : 0u);
}

// --- binarize weights, reorder K: wb[co][ (kh*3+kw)*256 + ci ] = sign(w[co][ci][kh][kw])
__global__ __launch_bounds__(256) void k_binw(const float* __restrict__ w,
                                              unsigned short* __restrict__ wb) {
    int g = blockIdx.x * 256 + threadIdx.x;
    if (g >= (int)WB_ELEMS) return;
    int co = g / KTOT;
    int r  = g - co * KTOT;
    int ci = r / 9;
    int koff = r - ci * 9;
    wb[co * KTOT + koff * C_CH + ci] = sign_bf16(w[g]);
}

// --- binarize x into zero-padded [nb][h+1][w+1][ci] bf16 via LDS transpose
__global__ __launch_bounds__(256) void k_binx(const float* __restrict__ x,
                                              unsigned short* __restrict__ xpad) {
    __shared__ unsigned short tile[32 * 66];   // [ci_l][hw], stride 66 kills bank conflicts
    const int t   = threadIdx.x;
    const int hw0 = blockIdx.x * 64;
    const int ci0 = blockIdx.y * 32;
    const int nb  = blockIdx.z;
    const int lhw = t & 63;
    const int cq  = t >> 6;    // 0..3
#pragma unroll
    for (int p = 0; p < 8; ++p) {
        int ci_l = cq + p * 4;
        float v = x[((size_t)(nb * C_CH + ci0 + ci_l)) * HW + hw0 + lhw];
        tile[ci_l * 66 + lhw] = sign_bf16(v);
    }
    __syncthreads();
    const int hwi = t >> 2;    // 0..63
    const int ch  = t & 3;     // 8 ci each
    const int hw  = hw0 + hwi;
    const int h   = hw / 56, w_ = hw - h * 56;
    s16x8 pk;
#pragma unroll
    for (int i = 0; i < 8; ++i) pk[i] = (short)tile[(ch * 8 + i) * 66 + hwi];
    size_t dst = ((size_t)((nb * HP + h + 1) * HP + (w_ + 1))) * C_CH + ci0 + ch * 8;
    *(s16x8*)(xpad + dst) = pk;   // 16B aligned contiguous
}

// --- implicit-GEMM conv: y[co][nsp] = sum_k wb[co][k] * xpad[...]; fused channel sum/sumsq
__global__ __launch_bounds__(256) void k_conv(const unsigned short* __restrict__ xpad,
                                              const unsigned short* __restrict__ wb,
                                              short* __restrict__ y16,
                                              float* __restrict__ gSum,
                                              float* __restrict__ gSqs) {
    __shared__ unsigned short lA[128 * 32];   // [co_row][k] 64B rows
    __shared__ unsigned short lB[128 * 32];   // [n_row][k]  64B rows
    __shared__ float sSum[128], sSqs[128];

    const int t    = threadIdx.x;
    const int wave = t >> 6, lane = t & 63;
    const int quad = lane >> 4, l16 = lane & 15;
    const int wm   = wave & 1, wn = wave >> 1;
    const int n0   = blockIdx.x * 128;
    const int co0  = blockIdx.y * 128;

    if (t < 128) { sSum[t] = 0.f; sSqs[t] = 0.f; }

    // loop-invariant staging addresses (lane -> 16 rows x 4 chunks of 16B)
    const int lr = lane >> 2;   // row within 16-row chunk
    const int lc = lane & 3;    // 16B chunk within 64B row
    const uint32_t aOff0 = (uint32_t)(co0 + wave * 32 + lr) * KTOT + lc * 8;
    const uint32_t aOff1 = aOff0 + 16 * KTOT;
    int nsp0 = n0 + wave * 32 + lr;
    int nb0 = nsp0 / HW; int hwr0 = nsp0 - nb0 * HW; int h0 = hwr0 / 56; int w0 = hwr0 - h0 * 56;
    const uint32_t bOff0 = (uint32_t)((nb0 * HP + h0) * HP + w0) * C_CH + lc * 8;
    int nsp1 = nsp0 + 16;
    int nb1 = nsp1 / HW; int hwr1 = nsp1 - nb1 * HW; int h1 = hwr1 / 56; int w1 = hwr1 - h1 * 56;
    const uint32_t bOff1 = (uint32_t)((nb1 * HP + h1) * HP + w1) * C_CH + lc * 8;

    f32x4 acc[4][4];
#pragma unroll
    for (int i = 0; i < 4; ++i)
#pragma unroll
        for (int j = 0; j < 4; ++j) acc[i][j] = (f32x4){0.f, 0.f, 0.f, 0.f};

    for (int kb = 0; kb < KTOT / 32; ++kb) {
        const int k0   = kb * 32;
        const int koff = k0 >> 8;              // (kh,kw) index 0..8
        const int ci0_ = k0 & 255;
        const int kh   = koff / 3;
        const int kw   = koff - kh * 3;
        const uint32_t bAdd = (uint32_t)(kh * HP + kw) * C_CH + ci0_;   // wave-uniform
        __syncthreads();
        gl16(wb + aOff0 + k0,     &lA[wave * 1024]);
        gl16(wb + aOff1 + k0,     &lA[wave * 1024 + 512]);
        gl16(xpad + bOff0 + bAdd, &lB[wave * 1024]);
        gl16(xpad + bOff1 + bAdd, &lB[wave * 1024 + 512]);
        __syncthreads();
        bf16x8 af[4], bf[4];
#pragma unroll
        for (int i = 0; i < 4; ++i)
            af[i] = *(const bf16x8*)&lA[(wm * 64 + i * 16 + l16) * 32 + quad * 8];
#pragma unroll
        for (int i = 0; i < 4; ++i)
            bf[i] = *(const bf16x8*)&lB[(wn * 64 + i * 16 + l16) * 32 + quad * 8];
#pragma unroll
        for (int mi = 0; mi < 4; ++mi)
#pragma unroll
            for (int ni = 0; ni < 4; ++ni)
                acc[mi][ni] = __builtin_amdgcn_mfma_f32_16x16x32_bf16(af[mi], bf[ni], acc[mi][ni], 0, 0, 0);
    }

    // epilogue: y16 store + per-channel partial sums
#pragma unroll
    for (int mi = 0; mi < 4; ++mi) {
#pragma unroll
        for (int r = 0; r < 4; ++r) {
            int m = co0 + wm * 64 + mi * 16 + quad * 4 + r;
            float s = 0.f, sq = 0.f;
#pragma unroll
            for (int ni = 0; ni < 4; ++ni) {
                float f = acc[mi][ni][r];     // exact integer
                int n = n0 + wn * 64 + ni * 16 + l16;
                y16[(uint32_t)m * NSP + n] = (short)(int)f;
                s += f; sq += f * f;
            }
#pragma unroll
            for (int off = 1; off < 16; off <<= 1) {
                s  += __shfl_xor(s, off);
                sq += __shfl_xor(sq, off);
            }
            if (l16 == 0) {
                atomicAdd(&sSum[m - co0], s);
                atomicAdd(&sSqs[m - co0], sq);
            }
        }
    }
    __syncthreads();
    if (t < 128) {
        atomicAdd(&gSum[co0 + t], sSum[t]);
        atomicAdd(&gSqs[co0 + t], sSqs[t]);
    }
}

// --- finalize BN stats into per-channel (a, b): out = a*y + b + x
__global__ void k_stats(const float* __restrict__ gSum, const float* __restrict__ gSqs,
                        const float* __restrict__ gamma, const float* __restrict__ beta,
                        float* __restrict__ ab) {
    int c = threadIdx.x;
    const float inv = 1.0f / (float)NSP;
    float mean = gSum[c] * inv;
    float var  = gSqs[c] * inv - mean * mean;
    float rstd = rsqrtf(var + 1e-5f);
    float a = gamma[c] * rstd;
    ab[c] = a;
    ab[C_CH + c] = beta[c] - mean * a;
}

// --- fused BN apply + residual
__global__ __launch_bounds__(256) void k_out(const short* __restrict__ y16,
                                             const float* __restrict__ x,
                                             const float* __restrict__ ab,
                                             float* __restrict__ out) {
    int g = blockIdx.x * 256 + threadIdx.x;       // NSP*C_CH/4 threads
    int hw4 = g % 784;
    int tmp = g / 784;
    int co  = tmp & 255;
    int nb  = tmp >> 8;
    float a = ab[co], b = ab[C_CH + co];
    s16x4 yv = *(const s16x4*)&y16[(uint32_t)co * NSP + nb * HW + hw4 * 4];
    size_t xi = ((size_t)(nb * C_CH + co)) * HW + hw4 * 4;
    f32x4v xv = *(const f32x4v*)&x[xi];
    f32x4v o;
#pragma unroll
    for (int i = 0; i < 4; ++i) o[i] = a * (float)yv[i] + b + xv[i];
    *(f32x4v*)&out[xi] = o;
}

extern "C" void kernel_launch(void* const* d_in, const int* in_sizes, int n_in,
                              void* d_out, int out_size, void* d_ws, size_t ws_size,
                              hipStream_t stream) {
    const float* x     = (const float*)d_in[0];
    const float* w     = (const float*)d_in[1];
    const float* gamma = (const float*)d_in[2];
    const float* beta  = (const float*)d_in[3];
    float* out = (float*)d_out;
    char* ws = (char*)d_ws;

    unsigned short* xpad = (unsigned short*)ws;
    unsigned short* wbp  = (unsigned short*)(ws + WB_OFF_B);
    short* y16           = (short*)(ws + Y_OFF_B);
    float* gSum          = (float*)(ws + STAT_OFF_B);
    float* gSqs          = gSum + 256;
    float* ab            = gSum + 512;

    hipMemsetAsync(xpad, 0, XPAD_BYTES, stream);                 // padding zeros
    hipMemsetAsync(gSum, 0, 512 * sizeof(float), stream);        // stat accumulators

    k_binw<<<(int)(WB_ELEMS / 256), 256, 0, stream>>>(w, wbp);
    k_binx<<<dim3(49, 8, 32), 256, 0, stream>>>(x, xpad);
    k_conv<<<dim3(NSP / 128, 2), 256, 0, stream>>>(xpad, wbp, y16, gSum, gSqs);
    k_stats<<<1, 256, 0, stream>>>(gSum, gSqs, gamma, beta, ab);
    k_out<<<(NSP * C_CH / 4) / 256, 256, 0, stream>>>(y16, x, ab, out);
}

// Round 2
// 336.832 us; speedup vs baseline: 1.2584x; 1.2584x over previous
//
#include <hip/hip_runtime.h>
#include <stdint.h>
#include <stddef.h>

// Problem constants
#define N_B   32
#define C_CH  256
#define H_S   56
#define W_S   56
#define HW    (H_S*W_S)        // 3136
#define NSP   (N_B*HW)         // 100352
#define KTOT  (C_CH*9)         // 2304 (bytes per row in i8)
#define HP    58               // padded spatial

// Workspace layout (bytes) — all i8 now
#define XPAD_BYTES ((size_t)N_B*HP*HP*C_CH)        // 27,557,888
#define WB_OFF_B   XPAD_BYTES
#define WB_BYTES   ((size_t)C_CH*KTOT)             // 589,824
#define Y_OFF_B    (WB_OFF_B + WB_BYTES)
#define STAT_OFF_B (Y_OFF_B + (size_t)C_CH*NSP*2)

typedef int    int4v  __attribute__((ext_vector_type(4)));
typedef short  s16x4  __attribute__((ext_vector_type(4)));
typedef char   char8  __attribute__((ext_vector_type(8)));
typedef float  f32x4v __attribute__((ext_vector_type(4)));

__device__ __forceinline__ void gl16(const void* g, void* l) {
    __builtin_amdgcn_global_load_lds((const __attribute__((address_space(1))) void*)g,
                                     (__attribute__((address_space(3))) void*)l, 16, 0, 0);
}

__device__ __forceinline__ char sign_i8(float v) {
    return v > 0.f ? (char)1 : (v < 0.f ? (char)-1 : (char)0);
}

// --- binarize weights (i8), reorder K; also zero the stat accumulators
__global__ __launch_bounds__(256) void k_binw(const float* __restrict__ w,
                                              char* __restrict__ wb,
                                              float* __restrict__ gStat) {
    int g = blockIdx.x * 256 + threadIdx.x;
    if (blockIdx.x == 0 && threadIdx.x < 512) gStat[threadIdx.x] = 0.f;
    if (g >= (int)WB_BYTES) return;
    int co = g / KTOT;
    int r  = g - co * KTOT;
    int ci = r / 9;
    int koff = r - ci * 9;
    wb[co * KTOT + koff * C_CH + ci] = sign_i8(w[g]);
}

// --- binarize x into zero-padded [nb][h+1][w+1][ci] i8 via LDS transpose
__global__ __launch_bounds__(256) void k_binx(const float* __restrict__ x,
                                              char* __restrict__ xpad) {
    __shared__ short tile[32 * 66];   // [ci_l][hw], stride 66 kills bank conflicts
    const int t   = threadIdx.x;
    const int hw0 = blockIdx.x * 64;
    const int ci0 = blockIdx.y * 32;
    const int nb  = blockIdx.z;
    const int lhw = t & 63;
    const int cq  = t >> 6;    // 0..3
#pragma unroll
    for (int p = 0; p < 8; ++p) {
        int ci_l = cq + p * 4;
        float v = x[((size_t)(nb * C_CH + ci0 + ci_l)) * HW + hw0 + lhw];
        tile[ci_l * 66 + lhw] = (short)sign_i8(v);
    }
    __syncthreads();
    const int hwi = t >> 2;    // 0..63
    const int ch  = t & 3;     // 8 ci each
    const int hw  = hw0 + hwi;
    const int h   = hw / 56, w_ = hw - h * 56;
    char8 pk;
#pragma unroll
    for (int i = 0; i < 8; ++i) pk[i] = (char)tile[(ch * 8 + i) * 66 + hwi];
    size_t dst = ((size_t)((nb * HP + h + 1) * HP + (w_ + 1))) * C_CH + ci0 + ch * 8;
    *(char8*)(xpad + dst) = pk;   // 8B aligned contiguous
}

// --- implicit-GEMM conv (i8 MFMA): y[co][nsp]; fused channel sum/sumsq
__global__ __launch_bounds__(256) void k_conv(const char* __restrict__ xpad,
                                              const char* __restrict__ wb,
                                              short* __restrict__ y16,
                                              float* __restrict__ gSum,
                                              float* __restrict__ gSqs) {
    __shared__ char lA[128 * 64];   // [co_row][k] 64B rows (BK=64 i8)
    __shared__ char lB[128 * 64];   // [n_row][k]
    __shared__ float sSum[128], sSqs[128];

    const int t    = threadIdx.x;
    const int wave = t >> 6, lane = t & 63;
    const int quad = lane >> 4, l16 = lane & 15;
    const int wm   = wave & 1, wn = wave >> 1;
    const int n0   = blockIdx.x * 128;
    const int co0  = blockIdx.y * 128;

    if (t < 128) { sSum[t] = 0.f; sSqs[t] = 0.f; }

    // loop-invariant staging addresses (lane -> 16 rows x 4 chunks of 16B)
    const int lr = lane >> 2;   // row within 16-row chunk
    const int lc = lane & 3;    // 16B chunk within 64B row
    const uint32_t aOff0 = (uint32_t)(co0 + wave * 32 + lr) * KTOT + lc * 16;
    const uint32_t aOff1 = aOff0 + 16 * KTOT;
    int nsp0 = n0 + wave * 32 + lr;
    int nb0 = nsp0 / HW; int hwr0 = nsp0 - nb0 * HW; int h0 = hwr0 / 56; int w0 = hwr0 - h0 * 56;
    const uint32_t bOff0 = (uint32_t)((nb0 * HP + h0) * HP + w0) * C_CH + lc * 16;
    int nsp1 = nsp0 + 16;
    int nb1 = nsp1 / HW; int hwr1 = nsp1 - nb1 * HW; int h1 = hwr1 / 56; int w1 = hwr1 - h1 * 56;
    const uint32_t bOff1 = (uint32_t)((nb1 * HP + h1) * HP + w1) * C_CH + lc * 16;

    int4v acc[4][4];
#pragma unroll
    for (int i = 0; i < 4; ++i)
#pragma unroll
        for (int j = 0; j < 4; ++j) acc[i][j] = (int4v){0, 0, 0, 0};

    for (int kb = 0; kb < KTOT / 64; ++kb) {              // 36 iterations
        const int k0   = kb * 64;
        const int koff = kb >> 2;              // (kh,kw) index 0..8
        const int ci0_ = (kb & 3) * 64;
        const int kh   = koff / 3;
        const int kw   = koff - kh * 3;
        const uint32_t bAdd = (uint32_t)(kh * HP + kw) * C_CH + ci0_;   // wave-uniform
        __syncthreads();
        gl16(wb + aOff0 + k0,     &lA[wave * 2048]);
        gl16(wb + aOff1 + k0,     &lA[wave * 2048 + 1024]);
        gl16(xpad + bOff0 + bAdd, &lB[wave * 2048]);
        gl16(xpad + bOff1 + bAdd, &lB[wave * 2048 + 1024]);
        __syncthreads();
        int4v af[4], bf[4];
#pragma unroll
        for (int i = 0; i < 4; ++i)
            af[i] = *(const int4v*)&lA[(wm * 64 + i * 16 + l16) * 64 + quad * 16];
#pragma unroll
        for (int i = 0; i < 4; ++i)
            bf[i] = *(const int4v*)&lB[(wn * 64 + i * 16 + l16) * 64 + quad * 16];
#pragma unroll
        for (int mi = 0; mi < 4; ++mi)
#pragma unroll
            for (int ni = 0; ni < 4; ++ni)
                acc[mi][ni] = __builtin_amdgcn_mfma_i32_16x16x64_i8(af[mi], bf[ni], acc[mi][ni], 0, 0, 0);
    }

    // epilogue: y16 store + per-channel partial sums
#pragma unroll
    for (int mi = 0; mi < 4; ++mi) {
#pragma unroll
        for (int r = 0; r < 4; ++r) {
            int m = co0 + wm * 64 + mi * 16 + quad * 4 + r;
            float s = 0.f, sq = 0.f;
#pragma unroll
            for (int ni = 0; ni < 4; ++ni) {
                int yi = acc[mi][ni][r];      // exact integer
                float f = (float)yi;
                int n = n0 + wn * 64 + ni * 16 + l16;
                y16[(uint32_t)m * NSP + n] = (short)yi;
                s += f; sq += f * f;
            }
#pragma unroll
            for (int off = 1; off < 16; off <<= 1) {
                s  += __shfl_xor(s, off);
                sq += __shfl_xor(sq, off);
            }
            if (l16 == 0) {
                atomicAdd(&sSum[m - co0], s);
                atomicAdd(&sSqs[m - co0], sq);
            }
        }
    }
    __syncthreads();
    if (t < 128) {
        atomicAdd(&gSum[co0 + t], sSum[t]);
        atomicAdd(&gSqs[co0 + t], sSqs[t]);
    }
}

// --- fused BN stats + apply + residual
__global__ __launch_bounds__(256) void k_out(const short* __restrict__ y16,
                                             const float* __restrict__ x,
                                             const float* __restrict__ gSum,
                                             const float* __restrict__ gSqs,
                                             const float* __restrict__ gamma,
                                             const float* __restrict__ beta,
                                             float* __restrict__ out) {
    int g = blockIdx.x * 256 + threadIdx.x;       // NSP*C_CH/4 threads
    int hw4 = g % 784;
    int tmp = g / 784;
    int co  = tmp & 255;
    int nb  = tmp >> 8;
    const float inv = 1.0f / (float)NSP;
    float mean = gSum[co] * inv;
    float var  = gSqs[co] * inv - mean * mean;
    float a = gamma[co] * rsqrtf(var + 1e-5f);
    float b = beta[co] - mean * a;
    s16x4 yv = *(const s16x4*)&y16[(uint32_t)co * NSP + nb * HW + hw4 * 4];
    size_t xi = ((size_t)(nb * C_CH + co)) * HW + hw4 * 4;
    f32x4v xv = *(const f32x4v*)&x[xi];
    f32x4v o;
#pragma unroll
    for (int i = 0; i < 4; ++i) o[i] = a * (float)yv[i] + b + xv[i];
    *(f32x4v*)&out[xi] = o;
}

extern "C" void kernel_launch(void* const* d_in, const int* in_sizes, int n_in,
                              void* d_out, int out_size, void* d_ws, size_t ws_size,
                              hipStream_t stream) {
    const float* x     = (const float*)d_in[0];
    const float* w     = (const float*)d_in[1];
    const float* gamma = (const float*)d_in[2];
    const float* beta  = (const float*)d_in[3];
    float* out = (float*)d_out;
    char* ws = (char*)d_ws;

    char*  xpad = ws;
    char*  wbp  = ws + WB_OFF_B;
    short* y16  = (short*)(ws + Y_OFF_B);
    float* gSum = (float*)(ws + STAT_OFF_B);
    float* gSqs = gSum + 256;

    hipMemsetAsync(xpad, 0, XPAD_BYTES, stream);                 // padding zeros

    k_binw<<<(int)((WB_BYTES + 255) / 256), 256, 0, stream>>>(w, wbp, gSum);
    k_binx<<<dim3(49, 8, 32), 256, 0, stream>>>(x, xpad);
    k_conv<<<dim3(NSP / 128, 2), 256, 0, stream>>>(xpad, wbp, y16, gSum, gSqs);
    k_out<<<(NSP * C_CH / 4) / 256, 256, 0, stream>>>(y16, x, gSum, gSqs, gamma, beta, out);
}